// Round 3
// baseline (129.508 us; speedup 1.0000x reference)
//
#include <hip/hip_runtime.h>

#define N_VOX 32768
#define CCH 128
#define EPSV 1e-5f

typedef __attribute__((ext_vector_type(8))) short bfrag;
typedef __attribute__((ext_vector_type(4))) float ffrag;
typedef __attribute__((ext_vector_type(2))) unsigned int u32x2;

__device__ __forceinline__ float bf2f(unsigned short u) {
    union { unsigned int i; float f; } c; c.i = ((unsigned int)u) << 16; return c.f;
}
__device__ __forceinline__ unsigned short f2bf(float f) {
    union { float f; unsigned int i; } c; c.f = f;
    unsigned int i = c.i;
    return (unsigned short)((i + 0x7FFFu + ((i >> 16) & 1u)) >> 16);
}
__device__ __forceinline__ unsigned int cvtpk(float lo, float hi) {
    unsigned int r;
    asm("v_cvt_pk_bf16_f32 %0, %1, %2" : "=v"(r) : "v"(lo), "v"(hi));
    return r;
}

// -------- Kernel 1: LayerNorm, x (C, N) fp32 -> h (N, C) bf16 --------
__global__ __launch_bounds__(256) void ln_kernel(const float* __restrict__ x,
                                                 const float* __restrict__ gamma,
                                                 const float* __restrict__ beta,
                                                 unsigned short* __restrict__ h) {
    __shared__ float xs[128 * 65];
    __shared__ float g[128], b[128];
    __shared__ float ps[256], pq[256];
    __shared__ float muS[64], rsS[64];
    int t = threadIdx.x;
    int v0 = blockIdx.x * 64;
    if (t < 128) { g[t] = gamma[t]; b[t] = beta[t]; }
    int vv = t & 63, cq = t >> 6;
    for (int cb = 0; cb < 32; cb++) {
        int c = cb * 4 + cq;
        xs[c * 65 + vv] = x[(size_t)c * N_VOX + v0 + vv];
    }
    __syncthreads();
    float s = 0.f, sq = 0.f;
    for (int i = 0; i < 32; i++) {
        float val = xs[(cq * 32 + i) * 65 + vv];
        s += val; sq += val * val;
    }
    ps[t] = s; pq[t] = sq;
    __syncthreads();
    if (t < 64) {
        float S = ps[t] + ps[t + 64] + ps[t + 128] + ps[t + 192];
        float Q = pq[t] + pq[t + 64] + pq[t + 128] + pq[t + 192];
        float mu = S * (1.0f / 128.0f);
        float var = Q * (1.0f / 128.0f) - mu * mu;
        muS[t] = mu; rsS[t] = rsqrtf(var + EPSV);
    }
    __syncthreads();
    int c8 = t & 15;
    for (int pass = 0; pass < 4; pass++) {
        int v = pass * 16 + (t >> 4);
        float mu = muS[v], rs = rsS[v];
        float val[8];
        #pragma unroll
        for (int i = 0; i < 8; i++) {
            int c = c8 * 8 + i;
            val[i] = (xs[c * 65 + v] - mu) * rs * g[c] + b[c];
        }
        uint4 q;
        q.x = cvtpk(val[0], val[1]);
        q.y = cvtpk(val[2], val[3]);
        q.z = cvtpk(val[4], val[5]);
        q.w = cvtpk(val[6], val[7]);
        *(uint4*)&h[(size_t)(v0 + v) * 128 + c8 * 8] = q;
    }
}

// -------- Kernel 2: QKV GEMM  qkv[v,o] = h[v,:] . w[o,:] + b[o] --------
// Q outputs (o < 128) pre-scaled by 32^-0.5.
__global__ __launch_bounds__(256) void qkv_gemm(const unsigned short* __restrict__ h,
                                                const float* __restrict__ w,
                                                const float* __restrict__ bias,
                                                unsigned short* __restrict__ qkv) {
    __shared__ __align__(16) unsigned short a_s[64 * 136];
    __shared__ __align__(16) unsigned short b_s[64 * 136];
    int t = threadIdx.x;
    int m0 = blockIdx.x * 64, o0 = blockIdx.y * 64;
    {
        int r4 = t >> 4, c8 = t & 15;
        #pragma unroll
        for (int pass = 0; pass < 4; pass++) {
            int r = pass * 16 + r4;
            *(uint4*)&a_s[r * 136 + c8 * 8] =
                *(const uint4*)&h[(size_t)(m0 + r) * 128 + c8 * 8];
            float4 w0 = *(const float4*)&w[(size_t)(o0 + r) * 128 + c8 * 8];
            float4 w1 = *(const float4*)&w[(size_t)(o0 + r) * 128 + c8 * 8 + 4];
            uint4 q;
            q.x = cvtpk(w0.x, w0.y);
            q.y = cvtpk(w0.z, w0.w);
            q.z = cvtpk(w1.x, w1.y);
            q.w = cvtpk(w1.z, w1.w);
            *(uint4*)&b_s[r * 136 + c8 * 8] = q;
        }
    }
    __syncthreads();
    int wvi = t >> 6, lane = t & 63, m = lane & 15, quad = lane >> 4;
    ffrag acc[4] = {ffrag{0,0,0,0}, ffrag{0,0,0,0}, ffrag{0,0,0,0}, ffrag{0,0,0,0}};
    #pragma unroll
    for (int kk = 0; kk < 4; kk++) {
        bfrag a = *(bfrag*)&a_s[(wvi * 16 + m) * 136 + kk * 32 + quad * 8];
        #pragma unroll
        for (int nt = 0; nt < 4; nt++) {
            bfrag bb = *(bfrag*)&b_s[(nt * 16 + m) * 136 + kk * 32 + quad * 8];
            acc[nt] = __builtin_amdgcn_mfma_f32_16x16x32_bf16(a, bb, acc[nt], 0, 0, 0);
        }
    }
    bool isq = (o0 < 128);
    #pragma unroll
    for (int nt = 0; nt < 4; nt++) {
        int o = o0 + nt * 16 + m;
        float bs = bias[o];
        int sec = o >> 7;
        int oc = o & 127;
        unsigned short* dst = qkv + (size_t)sec * ((size_t)N_VOX * 128);
        #pragma unroll
        for (int r = 0; r < 4; r++) {
            int vg = m0 + wvi * 16 + quad * 4 + r;
            float val = acc[nt][r] + bs;
            if (isq) val *= 0.17677669529663687f;
            dst[(size_t)vg * 128 + oc] = f2bf(val);
        }
    }
}

// -------- Kernel 3: neighborhood attention via MFMA (two-chunk V staging) --------
// Block = one 16-voxel z-column, 4 waves = 4 heads. Region = 9 xy x 18 z = 162
// rows (pad 176). V^T LDS halved vs round-1: stage regions [0,96) -> QK ->
// softmax -> PV chunk0 -> restage regions [96,176) into the SAME buffer
// (within-wave dep only, no barriers) -> PV chunk1.
// LDS 26.3KB (was 48.8KB) -> 6 blocks/CU by LDS (was 3).
#define VT_STRIDE 100
__global__ __launch_bounds__(256) void attn_kernel(const unsigned short* __restrict__ qb,
                                                   const unsigned short* __restrict__ kb,
                                                   const unsigned short* __restrict__ vb,
                                                   unsigned short* __restrict__ ob) {
    __shared__ unsigned int vjtab[176];                      // region idx -> voxel idx
    __shared__ __align__(16) unsigned short vt[4][32 * VT_STRIDE];  // per-head V^T chunk

    int t = threadIdx.x;
    int bidx = blockIdx.x;
    int zh = bidx & 1, yy = (bidx >> 1) & 31, xx = bidx >> 6;
    int z0 = zh << 4;
    int sx = min(max(xx - 1, 0), 29);
    int sy = min(max(yy - 1, 0), 29);
    int zr0 = min(max(z0 - 1, 0), 14);
    int vox0 = (xx << 10) + (yy << 5) + z0;

    if (t < 176) {
        int r = t < 162 ? t : 161;
        int rxy = r / 18;
        int rzv = r - rxy * 18;
        int ax = rxy / 3;
        int by = rxy - ax * 3;
        vjtab[t] = (unsigned)(((sx + ax) << 10) + ((sy + by) << 5) + (zr0 + rzv));
    }
    __syncthreads();

    int wave = t >> 6, lane = t & 63;
    int hq = lane >> 4;        // quad (k-chunk / row-chunk index)
    int m = lane & 15;
    int ch0 = wave * 32;
    unsigned short* vts = &vt[wave][0];
    const int cp = m;          // ch-pair index 0..15

    // ---- stage V^T chunk 0: regions [0, 96) ----
    #pragma unroll
    for (int u = 0; u < 6; u++) {
        int rb = u * 16 + hq * 4;
        unsigned int j0 = vjtab[rb + 0];
        unsigned int j1 = vjtab[rb + 1];
        unsigned int j2 = vjtab[rb + 2];
        unsigned int j3 = vjtab[rb + 3];
        unsigned int d0 = *(const unsigned int*)&vb[(size_t)j0 * 128 + ch0 + cp * 2];
        unsigned int d1 = *(const unsigned int*)&vb[(size_t)j1 * 128 + ch0 + cp * 2];
        unsigned int d2 = *(const unsigned int*)&vb[(size_t)j2 * 128 + ch0 + cp * 2];
        unsigned int d3 = *(const unsigned int*)&vb[(size_t)j3 * 128 + ch0 + cp * 2];
        unsigned int lo01 = __builtin_amdgcn_perm(d1, d0, 0x05040100u);
        unsigned int lo23 = __builtin_amdgcn_perm(d3, d2, 0x05040100u);
        unsigned int hi01 = __builtin_amdgcn_perm(d1, d0, 0x07060302u);
        unsigned int hi23 = __builtin_amdgcn_perm(d3, d2, 0x07060302u);
        u32x2 wlo; wlo.x = lo01; wlo.y = lo23;
        u32x2 whi; whi.x = hi01; whi.y = hi23;
        *(u32x2*)&vts[(2 * cp) * VT_STRIDE + rb] = wlo;
        *(u32x2*)&vts[(2 * cp + 1) * VT_STRIDE + rb] = whi;
    }

    // ---- QK^T (swapped): S^T[r][v], Q pre-scaled ----
    bfrag qf = *(const bfrag*)&qb[(size_t)(vox0 + m) * 128 + ch0 + hq * 8];
    ffrag s[11];
    #pragma unroll
    for (int f = 0; f < 11; f++) {
        unsigned int vj = vjtab[f * 16 + m];
        bfrag kf = *(const bfrag*)&kb[(size_t)vj * 128 + ch0 + hq * 8];
        s[f] = __builtin_amdgcn_mfma_f32_16x16x32_bf16(kf, qf, ffrag{0,0,0,0}, 0, 0, 0);
    }

    // ---- mask (z-window + r<162) + softmax, per voxel v = lane&15 ----
    int zv = z0 + m;
    int szv = min(max(zv - 1, 0), 29);
    unsigned int wz = (unsigned int)(szv - zr0);
    unsigned int rz = 4u * (unsigned int)hq;
    float mx = -1e30f;
    #pragma unroll
    for (int f = 0; f < 11; f++) {
        #pragma unroll
        for (int i = 0; i < 4; i++) {
            unsigned int ri = rz + (unsigned int)i;
            ri = min(ri, ri - 18u);            // mod-18 wrap
            bool valid = (ri - wz) <= 2u;
            if (f == 10) valid = valid && ((4 * hq + i) < 2);
            float sv = valid ? s[f][i] : -1e30f;
            s[f][i] = sv;
            mx = fmaxf(mx, sv);
        }
        rz = min(rz + 16u, rz - 2u);           // (rz+16) mod 18
    }
    mx = fmaxf(mx, __shfl_xor(mx, 16));
    mx = fmaxf(mx, __shfl_xor(mx, 32));
    float sum = 0.f;
    #pragma unroll
    for (int f = 0; f < 11; f++) {
        #pragma unroll
        for (int i = 0; i < 4; i++) {
            float p = __expf(s[f][i] - mx);
            s[f][i] = p;
            sum += p;
        }
    }
    sum += __shfl_xor(sum, 16);
    sum += __shfl_xor(sum, 32);
    float inv = 1.0f / sum;

    // ---- PV chunk 0: f = 0..5 ----
    ffrag acc0 = ffrag{0,0,0,0};
    ffrag acc1 = ffrag{0,0,0,0};
    const unsigned short* ab = &vt[wave][m * VT_STRIDE + hq * 4];
    #pragma unroll
    for (int f = 0; f < 6; f++) {
        u32x2 pb; pb.x = cvtpk(s[f][0], s[f][1]); pb.y = cvtpk(s[f][2], s[f][3]);
        u32x2 av0 = *(const u32x2*)&ab[f * 16];
        u32x2 av1 = *(const u32x2*)&ab[16 * VT_STRIDE + f * 16];
        asm("v_mfma_f32_16x16x16_bf16 %0, %1, %2, %0" : "+v"(acc0) : "v"(av0), "v"(pb));
        asm("v_mfma_f32_16x16x16_bf16 %0, %1, %2, %0" : "+v"(acc1) : "v"(av1), "v"(pb));
    }

    // ---- stage V^T chunk 1: regions [96, 176) into same buffer ----
    #pragma unroll
    for (int u = 6; u < 11; u++) {
        int rb = u * 16 + hq * 4;
        unsigned int j0 = vjtab[rb + 0];
        unsigned int j1 = vjtab[rb + 1];
        unsigned int j2 = vjtab[rb + 2];
        unsigned int j3 = vjtab[rb + 3];
        unsigned int d0 = *(const unsigned int*)&vb[(size_t)j0 * 128 + ch0 + cp * 2];
        unsigned int d1 = *(const unsigned int*)&vb[(size_t)j1 * 128 + ch0 + cp * 2];
        unsigned int d2 = *(const unsigned int*)&vb[(size_t)j2 * 128 + ch0 + cp * 2];
        unsigned int d3 = *(const unsigned int*)&vb[(size_t)j3 * 128 + ch0 + cp * 2];
        if (u == 10) {     // zero pad rows [162,176)
            if (rb + 0 >= 162) d0 = 0u;
            if (rb + 1 >= 162) d1 = 0u;
            if (rb + 2 >= 162) d2 = 0u;
            if (rb + 3 >= 162) d3 = 0u;
        }
        unsigned int lo01 = __builtin_amdgcn_perm(d1, d0, 0x05040100u);
        unsigned int lo23 = __builtin_amdgcn_perm(d3, d2, 0x05040100u);
        unsigned int hi01 = __builtin_amdgcn_perm(d1, d0, 0x07060302u);
        unsigned int hi23 = __builtin_amdgcn_perm(d3, d2, 0x07060302u);
        u32x2 wlo; wlo.x = lo01; wlo.y = lo23;
        u32x2 whi; whi.x = hi01; whi.y = hi23;
        int lc = rb - 96;
        *(u32x2*)&vts[(2 * cp) * VT_STRIDE + lc] = wlo;
        *(u32x2*)&vts[(2 * cp + 1) * VT_STRIDE + lc] = whi;
    }

    // ---- PV chunk 1: f = 6..10 ----
    #pragma unroll
    for (int f = 6; f < 11; f++) {
        u32x2 pb; pb.x = cvtpk(s[f][0], s[f][1]); pb.y = cvtpk(s[f][2], s[f][3]);
        int lc = f * 16 - 96;
        u32x2 av0 = *(const u32x2*)&ab[lc];
        u32x2 av1 = *(const u32x2*)&ab[16 * VT_STRIDE + lc];
        asm("v_mfma_f32_16x16x16_bf16 %0, %1, %2, %0" : "+v"(acc0) : "v"(av0), "v"(pb));
        asm("v_mfma_f32_16x16x16_bf16 %0, %1, %2, %0" : "+v"(acc1) : "v"(av1), "v"(pb));
    }

    // ---- epilogue: scale by 1/sum, pack bf16, store O[vox][ch] ----
    size_t obase = (size_t)(vox0 + m) * 128 + ch0 + hq * 4;
    {
        u32x2 ov;
        ov.x = cvtpk(acc0[0] * inv, acc0[1] * inv);
        ov.y = cvtpk(acc0[2] * inv, acc0[3] * inv);
        *(u32x2*)&ob[obase] = ov;
    }
    {
        u32x2 ov;
        ov.x = cvtpk(acc1[0] * inv, acc1[1] * inv);
        ov.y = cvtpk(acc1[2] * inv, acc1[3] * inv);
        *(u32x2*)&ob[obase + 16] = ov;
    }
}

// -------- Kernel 4: proj GEMM + bias + residual + transpose to (C, N) --------
__global__ __launch_bounds__(256) void proj_gemm(const unsigned short* __restrict__ a,
                                                 const float* __restrict__ w,
                                                 const float* __restrict__ bias,
                                                 const float* __restrict__ xres,
                                                 float* __restrict__ out) {
    __shared__ __align__(16) unsigned short a_s[64 * 136];
    __shared__ __align__(16) unsigned short b_s[64 * 136];
    int t = threadIdx.x;
    int m0 = blockIdx.x * 64, o0 = blockIdx.y * 64;
    {
        int r4 = t >> 4, c8 = t & 15;
        #pragma unroll
        for (int pass = 0; pass < 4; pass++) {
            int r = pass * 16 + r4;
            *(uint4*)&a_s[r * 136 + c8 * 8] =
                *(const uint4*)&a[(size_t)(m0 + r) * 128 + c8 * 8];
            float4 w0 = *(const float4*)&w[(size_t)(o0 + r) * 128 + c8 * 8];
            float4 w1 = *(const float4*)&w[(size_t)(o0 + r) * 128 + c8 * 8 + 4];
            uint4 q;
            q.x = cvtpk(w0.x, w0.y);
            q.y = cvtpk(w0.z, w0.w);
            q.z = cvtpk(w1.x, w1.y);
            q.w = cvtpk(w1.z, w1.w);
            *(uint4*)&b_s[r * 136 + c8 * 8] = q;
        }
    }
    __syncthreads();
    int wvi = t >> 6, lane = t & 63, m = lane & 15, quad = lane >> 4;
    ffrag acc[4] = {ffrag{0,0,0,0}, ffrag{0,0,0,0}, ffrag{0,0,0,0}, ffrag{0,0,0,0}};
    #pragma unroll
    for (int kk = 0; kk < 4; kk++) {
        bfrag av = *(bfrag*)&a_s[(wvi * 16 + m) * 136 + kk * 32 + quad * 8];
        #pragma unroll
        for (int nt = 0; nt < 4; nt++) {
            bfrag bb = *(bfrag*)&b_s[(nt * 16 + m) * 136 + kk * 32 + quad * 8];
            acc[nt] = __builtin_amdgcn_mfma_f32_16x16x32_bf16(av, bb, acc[nt], 0, 0, 0);
        }
    }
    #pragma unroll
    for (int nt = 0; nt < 4; nt++) {
        int o = o0 + nt * 16 + m;
        float bs = bias[o];
        int vg = m0 + wvi * 16 + quad * 4;
        float4 r = *(const float4*)&xres[(size_t)o * N_VOX + vg];
        float4 ov;
        ov.x = acc[nt][0] + bs + r.x;
        ov.y = acc[nt][1] + bs + r.y;
        ov.z = acc[nt][2] + bs + r.z;
        ov.w = acc[nt][3] + bs + r.w;
        *(float4*)&out[(size_t)o * N_VOX + vg] = ov;
    }
}

extern "C" void kernel_launch(void* const* d_in, const int* in_sizes, int n_in,
                              void* d_out, int out_size, void* d_ws, size_t ws_size,
                              hipStream_t stream) {
    const float* x      = (const float*)d_in[0];
    const float* gamma  = (const float*)d_in[1];
    const float* beta   = (const float*)d_in[2];
    const float* qkv_w  = (const float*)d_in[3];
    const float* qkv_b  = (const float*)d_in[4];
    const float* proj_w = (const float*)d_in[5];
    const float* proj_b = (const float*)d_in[6];
    float* out = (float*)d_out;

    unsigned short* h    = (unsigned short*)d_ws;                           // 8 MB
    unsigned short* qkv  = (unsigned short*)((char*)d_ws + (8u << 20));     // 24 MB
    unsigned short* attn = h;                                               // reuse h

    hipLaunchKernelGGL(ln_kernel, dim3(512), dim3(256), 0, stream, x, gamma, beta, h);
    hipLaunchKernelGGL(qkv_gemm, dim3(512, 6), dim3(256), 0, stream, h, qkv_w, qkv_b, qkv);
    const unsigned short* qb = qkv;
    const unsigned short* kb = qkv + (size_t)N_VOX * 128;
    const unsigned short* vb = qkv + (size_t)2 * N_VOX * 128;
    hipLaunchKernelGGL(attn_kernel, dim3(2048), dim3(256), 0, stream, qb, kb, vb, attn);
    hipLaunchKernelGGL(proj_gemm, dim3(512, 2), dim3(256), 0, stream, attn, proj_w, proj_b, x, out);
}

// Round 5
// 119.793 us; speedup vs baseline: 1.0811x; 1.0811x over previous
//
#include <hip/hip_runtime.h>

#define N_VOX 32768
#define CCH 128
#define EPSV 1e-5f

typedef __attribute__((ext_vector_type(8))) short bfrag;
typedef __attribute__((ext_vector_type(4))) float ffrag;
typedef __attribute__((ext_vector_type(2))) unsigned int u32x2;

__device__ __forceinline__ float bf2f(unsigned short u) {
    union { unsigned int i; float f; } c; c.i = ((unsigned int)u) << 16; return c.f;
}
__device__ __forceinline__ unsigned short f2bf(float f) {
    union { float f; unsigned int i; } c; c.f = f;
    unsigned int i = c.i;
    return (unsigned short)((i + 0x7FFFu + ((i >> 16) & 1u)) >> 16);
}
__device__ __forceinline__ unsigned int cvtpk(float lo, float hi) {
    unsigned int r;
    asm("v_cvt_pk_bf16_f32 %0, %1, %2" : "=v"(r) : "v"(lo), "v"(hi));
    return r;
}

// -------- Kernel 1: LayerNorm, x (C, N) fp32 -> h (N, C) bf16 --------
__global__ __launch_bounds__(256) void ln_kernel(const float* __restrict__ x,
                                                 const float* __restrict__ gamma,
                                                 const float* __restrict__ beta,
                                                 unsigned short* __restrict__ h) {
    __shared__ float xs[128 * 65];
    __shared__ float g[128], b[128];
    __shared__ float ps[256], pq[256];
    __shared__ float muS[64], rsS[64];
    int t = threadIdx.x;
    int v0 = blockIdx.x * 64;
    if (t < 128) { g[t] = gamma[t]; b[t] = beta[t]; }
    int vv = t & 63, cq = t >> 6;
    for (int cb = 0; cb < 32; cb++) {
        int c = cb * 4 + cq;
        xs[c * 65 + vv] = x[(size_t)c * N_VOX + v0 + vv];
    }
    __syncthreads();
    float s = 0.f, sq = 0.f;
    for (int i = 0; i < 32; i++) {
        float val = xs[(cq * 32 + i) * 65 + vv];
        s += val; sq += val * val;
    }
    ps[t] = s; pq[t] = sq;
    __syncthreads();
    if (t < 64) {
        float S = ps[t] + ps[t + 64] + ps[t + 128] + ps[t + 192];
        float Q = pq[t] + pq[t + 64] + pq[t + 128] + pq[t + 192];
        float mu = S * (1.0f / 128.0f);
        float var = Q * (1.0f / 128.0f) - mu * mu;
        muS[t] = mu; rsS[t] = rsqrtf(var + EPSV);
    }
    __syncthreads();
    int c8 = t & 15;
    for (int pass = 0; pass < 4; pass++) {
        int v = pass * 16 + (t >> 4);
        float mu = muS[v], rs = rsS[v];
        float val[8];
        #pragma unroll
        for (int i = 0; i < 8; i++) {
            int c = c8 * 8 + i;
            val[i] = (xs[c * 65 + v] - mu) * rs * g[c] + b[c];
        }
        uint4 q;
        q.x = cvtpk(val[0], val[1]);
        q.y = cvtpk(val[2], val[3]);
        q.z = cvtpk(val[4], val[5]);
        q.w = cvtpk(val[6], val[7]);
        *(uint4*)&h[(size_t)(v0 + v) * 128 + c8 * 8] = q;
    }
}

// -------- Kernel 2: QKV GEMM  qkv[v,o] = h[v,:] . w[o,:] + b[o] --------
// Q outputs (o < 128) pre-scaled by 32^-0.5.
__global__ __launch_bounds__(256) void qkv_gemm(const unsigned short* __restrict__ h,
                                                const float* __restrict__ w,
                                                const float* __restrict__ bias,
                                                unsigned short* __restrict__ qkv) {
    __shared__ __align__(16) unsigned short a_s[64 * 136];
    __shared__ __align__(16) unsigned short b_s[64 * 136];
    int t = threadIdx.x;
    int m0 = blockIdx.x * 64, o0 = blockIdx.y * 64;
    {
        int r4 = t >> 4, c8 = t & 15;
        #pragma unroll
        for (int pass = 0; pass < 4; pass++) {
            int r = pass * 16 + r4;
            *(uint4*)&a_s[r * 136 + c8 * 8] =
                *(const uint4*)&h[(size_t)(m0 + r) * 128 + c8 * 8];
            float4 w0 = *(const float4*)&w[(size_t)(o0 + r) * 128 + c8 * 8];
            float4 w1 = *(const float4*)&w[(size_t)(o0 + r) * 128 + c8 * 8 + 4];
            uint4 q;
            q.x = cvtpk(w0.x, w0.y);
            q.y = cvtpk(w0.z, w0.w);
            q.z = cvtpk(w1.x, w1.y);
            q.w = cvtpk(w1.z, w1.w);
            *(uint4*)&b_s[r * 136 + c8 * 8] = q;
        }
    }
    __syncthreads();
    int wvi = t >> 6, lane = t & 63, m = lane & 15, quad = lane >> 4;
    ffrag acc[4] = {ffrag{0,0,0,0}, ffrag{0,0,0,0}, ffrag{0,0,0,0}, ffrag{0,0,0,0}};
    #pragma unroll
    for (int kk = 0; kk < 4; kk++) {
        bfrag a = *(bfrag*)&a_s[(wvi * 16 + m) * 136 + kk * 32 + quad * 8];
        #pragma unroll
        for (int nt = 0; nt < 4; nt++) {
            bfrag bb = *(bfrag*)&b_s[(nt * 16 + m) * 136 + kk * 32 + quad * 8];
            acc[nt] = __builtin_amdgcn_mfma_f32_16x16x32_bf16(a, bb, acc[nt], 0, 0, 0);
        }
    }
    bool isq = (o0 < 128);
    #pragma unroll
    for (int nt = 0; nt < 4; nt++) {
        int o = o0 + nt * 16 + m;
        float bs = bias[o];
        int sec = o >> 7;
        int oc = o & 127;
        unsigned short* dst = qkv + (size_t)sec * ((size_t)N_VOX * 128);
        #pragma unroll
        for (int r = 0; r < 4; r++) {
            int vg = m0 + wvi * 16 + quad * 4 + r;
            float val = acc[nt][r] + bs;
            if (isq) val *= 0.17677669529663687f;
            dst[(size_t)vg * 128 + oc] = f2bf(val);
        }
    }
}

// -------- Kernel 3: neighborhood attention via MFMA --------
// Byte-identical to the verified round-1 kernel EXCEPT the XCD-aware block
// swizzle: hw blockIdx is dispatched round-robin across the 8 XCDs, so
// logical bidx = (hw%8)*256 + hw/8 gives each XCD a CONTIGUOUS run of 256
// z-columns (4 x-planes, ~3-5MB of Q/K/V) that fits its private 4MB L2.
// Adjacent columns share 2/3 of their K/V region -> those reads become
// L2 hits instead of L3/HBM (the 24MB qkv buffer is not L2-resident).
#define VT_STRIDE 188
__global__ __launch_bounds__(256) void attn_kernel(const unsigned short* __restrict__ qb,
                                                   const unsigned short* __restrict__ kb,
                                                   const unsigned short* __restrict__ vb,
                                                   unsigned short* __restrict__ ob) {
    __shared__ unsigned int vjtab[176];                      // region idx -> voxel idx
    __shared__ __align__(16) unsigned short vt[4][32 * VT_STRIDE];  // per-head V^T slice

    int t = threadIdx.x;
    // XCD-aware swizzle (bijective: 2048 = 8 XCDs x 256 blocks)
    int hw = blockIdx.x;
    int bidx = (hw & 7) * 256 + (hw >> 3);
    int zh = bidx & 1, yy = (bidx >> 1) & 31, xx = bidx >> 6;
    int z0 = zh << 4;
    int sx = min(max(xx - 1, 0), 29);
    int sy = min(max(yy - 1, 0), 29);
    int zr0 = min(max(z0 - 1, 0), 14);
    int vox0 = (xx << 10) + (yy << 5) + z0;

    if (t < 176) {
        int r = t < 162 ? t : 161;
        int rxy = r / 18;
        int rzv = r - rxy * 18;
        int ax = rxy / 3;
        int by = rxy - ax * 3;
        vjtab[t] = (unsigned)(((sx + ax) << 10) + ((sy + by) << 5) + (zr0 + rzv));
    }
    __syncthreads();

    int wave = t >> 6, lane = t & 63;
    int hq = lane >> 4;        // quad (k-chunk / row-chunk index)
    int m = lane & 15;
    int ch0 = wave * 32;

    // ---- stage V^T slice for this head: vt[wave][ch_local][region] ----
    unsigned short* vts = &vt[wave][0];
    {
        const int cp = m;      // ch-pair index 0..15
        #pragma unroll
        for (int u = 0; u < 11; u++) {
            int rb = u * 16 + hq * 4;
            unsigned int j0 = vjtab[rb + 0];
            unsigned int j1 = vjtab[rb + 1];
            unsigned int j2 = vjtab[rb + 2];
            unsigned int j3 = vjtab[rb + 3];
            unsigned int d0 = *(const unsigned int*)&vb[(size_t)j0 * 128 + ch0 + cp * 2];
            unsigned int d1 = *(const unsigned int*)&vb[(size_t)j1 * 128 + ch0 + cp * 2];
            unsigned int d2 = *(const unsigned int*)&vb[(size_t)j2 * 128 + ch0 + cp * 2];
            unsigned int d3 = *(const unsigned int*)&vb[(size_t)j3 * 128 + ch0 + cp * 2];
            if (u == 10) {     // zero pad rows [162,176) (NaN-safety for P*V)
                if (rb + 0 >= 162) d0 = 0u;
                if (rb + 1 >= 162) d1 = 0u;
                if (rb + 2 >= 162) d2 = 0u;
                if (rb + 3 >= 162) d3 = 0u;
            }
            unsigned int lo01 = __builtin_amdgcn_perm(d1, d0, 0x05040100u);
            unsigned int lo23 = __builtin_amdgcn_perm(d3, d2, 0x05040100u);
            unsigned int hi01 = __builtin_amdgcn_perm(d1, d0, 0x07060302u);
            unsigned int hi23 = __builtin_amdgcn_perm(d3, d2, 0x07060302u);
            u32x2 wlo; wlo.x = lo01; wlo.y = lo23;
            u32x2 whi; whi.x = hi01; whi.y = hi23;
            *(u32x2*)&vts[(2 * cp) * VT_STRIDE + rb] = wlo;
            *(u32x2*)&vts[(2 * cp + 1) * VT_STRIDE + rb] = whi;
        }
    }

    // ---- QK^T: S^T[r][v] = sum_ch K[vj(r)][ch] * Q[v][ch]  (Q pre-scaled) ----
    bfrag qf = *(const bfrag*)&qb[(size_t)(vox0 + m) * 128 + ch0 + hq * 8];
    ffrag s[11];
    #pragma unroll
    for (int f = 0; f < 11; f++) {
        unsigned int vj = vjtab[f * 16 + m];
        bfrag kf = *(const bfrag*)&kb[(size_t)vj * 128 + ch0 + hq * 8];
        s[f] = __builtin_amdgcn_mfma_f32_16x16x32_bf16(kf, qf, ffrag{0,0,0,0}, 0, 0, 0);
    }

    // ---- mask (z-window + r<162) + softmax over region, per voxel v = lane&15 ----
    int zv = z0 + m;
    int szv = min(max(zv - 1, 0), 29);
    unsigned int wz = (unsigned int)(szv - zr0);
    unsigned int rz = 4u * (unsigned int)hq;   // rz(r) for r = 16f + 4*hq, f=0
    float mx = -1e30f;
    #pragma unroll
    for (int f = 0; f < 11; f++) {
        #pragma unroll
        for (int i = 0; i < 4; i++) {
            unsigned int ri = rz + (unsigned int)i;
            ri = min(ri, ri - 18u);            // mod-18 wrap (single-wrap trick)
            bool valid = (ri - wz) <= 2u;      // unsigned window test
            if (f == 10) valid = valid && ((4 * hq + i) < 2);  // r < 162
            float sv = valid ? s[f][i] : -1e30f;
            s[f][i] = sv;
            mx = fmaxf(mx, sv);
        }
        rz = min(rz + 16u, rz - 2u);           // (rz+16) mod 18
    }
    mx = fmaxf(mx, __shfl_xor(mx, 16));
    mx = fmaxf(mx, __shfl_xor(mx, 32));
    float sum = 0.f;
    #pragma unroll
    for (int f = 0; f < 11; f++) {
        #pragma unroll
        for (int i = 0; i < 4; i++) {
            float p = __expf(s[f][i] - mx);
            s[f][i] = p;
            sum += p;
        }
    }
    sum += __shfl_xor(sum, 16);
    sum += __shfl_xor(sum, 32);
    float inv = 1.0f / sum;

    // ---- PV: O^T[ch][v] = sum_r V^T[ch][r] * P^T[r][v], P from regs ----
    ffrag acc0 = ffrag{0,0,0,0};
    ffrag acc1 = ffrag{0,0,0,0};
    const unsigned short* ab = &vt[wave][m * VT_STRIDE + hq * 4];
    #pragma unroll
    for (int f = 0; f < 11; f++) {
        u32x2 pb; pb.x = cvtpk(s[f][0], s[f][1]); pb.y = cvtpk(s[f][2], s[f][3]);
        u32x2 av0 = *(const u32x2*)&ab[f * 16];
        u32x2 av1 = *(const u32x2*)&ab[16 * VT_STRIDE + f * 16];
        asm("v_mfma_f32_16x16x16_bf16 %0, %1, %2, %0" : "+v"(acc0) : "v"(av0), "v"(pb));
        asm("v_mfma_f32_16x16x16_bf16 %0, %1, %2, %0" : "+v"(acc1) : "v"(av1), "v"(pb));
    }

    // ---- epilogue: scale by 1/sum, pack bf16, store O[vox][ch] ----
    size_t obase = (size_t)(vox0 + m) * 128 + ch0 + hq * 4;
    {
        u32x2 ov;
        ov.x = cvtpk(acc0[0] * inv, acc0[1] * inv);
        ov.y = cvtpk(acc0[2] * inv, acc0[3] * inv);
        *(u32x2*)&ob[obase] = ov;
    }
    {
        u32x2 ov;
        ov.x = cvtpk(acc1[0] * inv, acc1[1] * inv);
        ov.y = cvtpk(acc1[2] * inv, acc1[3] * inv);
        *(u32x2*)&ob[obase + 16] = ov;
    }
}

// -------- Kernel 4: proj GEMM + bias + residual + transpose to (C, N) --------
__global__ __launch_bounds__(256) void proj_gemm(const unsigned short* __restrict__ a,
                                                 const float* __restrict__ w,
                                                 const float* __restrict__ bias,
                                                 const float* __restrict__ xres,
                                                 float* __restrict__ out) {
    __shared__ __align__(16) unsigned short a_s[64 * 136];
    __shared__ __align__(16) unsigned short b_s[64 * 136];
    int t = threadIdx.x;
    int m0 = blockIdx.x * 64, o0 = blockIdx.y * 64;
    {
        int r4 = t >> 4, c8 = t & 15;
        #pragma unroll
        for (int pass = 0; pass < 4; pass++) {
            int r = pass * 16 + r4;
            *(uint4*)&a_s[r * 136 + c8 * 8] =
                *(const uint4*)&a[(size_t)(m0 + r) * 128 + c8 * 8];
            float4 w0 = *(const float4*)&w[(size_t)(o0 + r) * 128 + c8 * 8];
            float4 w1 = *(const float4*)&w[(size_t)(o0 + r) * 128 + c8 * 8 + 4];
            uint4 q;
            q.x = cvtpk(w0.x, w0.y);
            q.y = cvtpk(w0.z, w0.w);
            q.z = cvtpk(w1.x, w1.y);
            q.w = cvtpk(w1.z, w1.w);
            *(uint4*)&b_s[r * 136 + c8 * 8] = q;
        }
    }
    __syncthreads();
    int wvi = t >> 6, lane = t & 63, m = lane & 15, quad = lane >> 4;
    ffrag acc[4] = {ffrag{0,0,0,0}, ffrag{0,0,0,0}, ffrag{0,0,0,0}, ffrag{0,0,0,0}};
    #pragma unroll
    for (int kk = 0; kk < 4; kk++) {
        bfrag av = *(bfrag*)&a_s[(wvi * 16 + m) * 136 + kk * 32 + quad * 8];
        #pragma unroll
        for (int nt = 0; nt < 4; nt++) {
            bfrag bb = *(bfrag*)&b_s[(nt * 16 + m) * 136 + kk * 32 + quad * 8];
            acc[nt] = __builtin_amdgcn_mfma_f32_16x16x32_bf16(av, bb, acc[nt], 0, 0, 0);
        }
    }
    #pragma unroll
    for (int nt = 0; nt < 4; nt++) {
        int o = o0 + nt * 16 + m;
        float bs = bias[o];
        int vg = m0 + wvi * 16 + quad * 4;
        float4 r = *(const float4*)&xres[(size_t)o * N_VOX + vg];
        float4 ov;
        ov.x = acc[nt][0] + bs + r.x;
        ov.y = acc[nt][1] + bs + r.y;
        ov.z = acc[nt][2] + bs + r.z;
        ov.w = acc[nt][3] + bs + r.w;
        *(float4*)&out[(size_t)o * N_VOX + vg] = ov;
    }
}

extern "C" void kernel_launch(void* const* d_in, const int* in_sizes, int n_in,
                              void* d_out, int out_size, void* d_ws, size_t ws_size,
                              hipStream_t stream) {
    const float* x      = (const float*)d_in[0];
    const float* gamma  = (const float*)d_in[1];
    const float* beta   = (const float*)d_in[2];
    const float* qkv_w  = (const float*)d_in[3];
    const float* qkv_b  = (const float*)d_in[4];
    const float* proj_w = (const float*)d_in[5];
    const float* proj_b = (const float*)d_in[6];
    float* out = (float*)d_out;

    unsigned short* h    = (unsigned short*)d_ws;                           // 8 MB
    unsigned short* qkv  = (unsigned short*)((char*)d_ws + (8u << 20));     // 24 MB
    unsigned short* attn = h;                                               // reuse h

    hipLaunchKernelGGL(ln_kernel, dim3(512), dim3(256), 0, stream, x, gamma, beta, h);
    hipLaunchKernelGGL(qkv_gemm, dim3(512, 6), dim3(256), 0, stream, h, qkv_w, qkv_b, qkv);
    const unsigned short* qb = qkv;
    const unsigned short* kb = qkv + (size_t)N_VOX * 128;
    const unsigned short* vb = qkv + (size_t)2 * N_VOX * 128;
    hipLaunchKernelGGL(attn_kernel, dim3(2048), dim3(256), 0, stream, qb, kb, vb, attn);
    hipLaunchKernelGGL(proj_gemm, dim3(512, 2), dim3(256), 0, stream, attn, proj_w, proj_b, x, out);
}

// Round 6
// 118.221 us; speedup vs baseline: 1.0955x; 1.0133x over previous
//
#include <hip/hip_runtime.h>

#define N_VOX 32768
#define CCH 128
#define EPSV 1e-5f

typedef __attribute__((ext_vector_type(8))) short bfrag;
typedef __attribute__((ext_vector_type(4))) float ffrag;
typedef __attribute__((ext_vector_type(2))) unsigned int u32x2;

__device__ __forceinline__ float bf2f(unsigned short u) {
    union { unsigned int i; float f; } c; c.i = ((unsigned int)u) << 16; return c.f;
}
__device__ __forceinline__ unsigned short f2bf(float f) {
    union { float f; unsigned int i; } c; c.f = f;
    unsigned int i = c.i;
    return (unsigned short)((i + 0x7FFFu + ((i >> 16) & 1u)) >> 16);
}
__device__ __forceinline__ unsigned int cvtpk(float lo, float hi) {
    unsigned int r;
    asm("v_cvt_pk_bf16_f32 %0, %1, %2" : "=v"(r) : "v"(lo), "v"(hi));
    return r;
}

// -------- Kernel 1: fused LayerNorm + QKV GEMM --------
// Block = 64 voxels. LN in registers (coalesced x loads, LDS cross-wave
// reduce), normalized bf16 tile written straight into the GEMM A-tile --
// no h intermediate in global memory. blockIdx.x = o-group (3 o-tiles of 64
// each), blockIdx.y = voxel tile. LN is duplicated across the og=2 split
// (cost: extra 16MB x read + LN VALU) in exchange for killing the ln
// dispatch + 8MB h round-trip + one launch gap. Q outputs (o<128)
// pre-scaled by 32^-0.5.
__global__ __launch_bounds__(256) void ln_qkv(const float* __restrict__ x,
                                              const float* __restrict__ gamma,
                                              const float* __restrict__ beta,
                                              const float* __restrict__ w,
                                              const float* __restrict__ bias,
                                              unsigned short* __restrict__ qkv) {
    __shared__ __align__(16) unsigned short a_s[64 * 136];
    __shared__ __align__(16) unsigned short b_s[64 * 136];
    __shared__ float ps[256], pq[256];
    __shared__ float muS[64], rsS[64];
    __shared__ float g[128], bta[128];
    int t = threadIdx.x;
    int og = blockIdx.x;            // o-group: tiles og*192 .. og*192+191
    int v0 = blockIdx.y * 64;
    if (t < 128) { g[t] = gamma[t]; bta[t] = beta[t]; }
    int cq = t >> 6, v = t & 63;
    // ---- LN phase: each wave owns 32 channels, all 64 voxels ----
    float xr[32];
    float s = 0.f, sq = 0.f;
    #pragma unroll
    for (int i = 0; i < 32; i++) {
        float val = x[(size_t)(cq * 32 + i) * N_VOX + v0 + v];
        xr[i] = val; s += val; sq += val * val;
    }
    ps[t] = s; pq[t] = sq;
    __syncthreads();
    if (t < 64) {
        float S = ps[t] + ps[t + 64] + ps[t + 128] + ps[t + 192];
        float Q = pq[t] + pq[t + 64] + pq[t + 128] + pq[t + 192];
        float mu = S * (1.0f / 128.0f);
        float var = Q * (1.0f / 128.0f) - mu * mu;
        muS[t] = mu; rsS[t] = rsqrtf(var + EPSV);
    }
    __syncthreads();
    {
        float mu = muS[v], rs = rsS[v];
        #pragma unroll
        for (int i8 = 0; i8 < 4; i8++) {
            float val[8];
            #pragma unroll
            for (int k = 0; k < 8; k++) {
                int c = cq * 32 + i8 * 8 + k;
                val[k] = (xr[i8 * 8 + k] - mu) * rs * g[c] + bta[c];
            }
            uint4 q;
            q.x = cvtpk(val[0], val[1]);
            q.y = cvtpk(val[2], val[3]);
            q.z = cvtpk(val[4], val[5]);
            q.w = cvtpk(val[6], val[7]);
            *(uint4*)&a_s[v * 136 + cq * 32 + i8 * 8] = q;
        }
    }
    __syncthreads();
    // ---- GEMM phase: 3 o-tiles of 64 ----
    int lane = t & 63, wvi = t >> 6, m = lane & 15, quad = lane >> 4;
    bfrag areg[4];
    #pragma unroll
    for (int kk = 0; kk < 4; kk++)
        areg[kk] = *(bfrag*)&a_s[(wvi * 16 + m) * 136 + kk * 32 + quad * 8];
    for (int t0 = 0; t0 < 3; t0++) {
        int o0 = og * 192 + t0 * 64;
        {
            int r4 = t >> 4, c8 = t & 15;
            #pragma unroll
            for (int pass = 0; pass < 4; pass++) {
                int r = pass * 16 + r4;
                float4 w0 = *(const float4*)&w[(size_t)(o0 + r) * 128 + c8 * 8];
                float4 w1 = *(const float4*)&w[(size_t)(o0 + r) * 128 + c8 * 8 + 4];
                uint4 q;
                q.x = cvtpk(w0.x, w0.y);
                q.y = cvtpk(w0.z, w0.w);
                q.z = cvtpk(w1.x, w1.y);
                q.w = cvtpk(w1.z, w1.w);
                *(uint4*)&b_s[r * 136 + c8 * 8] = q;
            }
        }
        __syncthreads();
        ffrag acc[4] = {ffrag{0,0,0,0}, ffrag{0,0,0,0}, ffrag{0,0,0,0}, ffrag{0,0,0,0}};
        #pragma unroll
        for (int kk = 0; kk < 4; kk++) {
            #pragma unroll
            for (int nt = 0; nt < 4; nt++) {
                bfrag bb = *(bfrag*)&b_s[(nt * 16 + m) * 136 + kk * 32 + quad * 8];
                acc[nt] = __builtin_amdgcn_mfma_f32_16x16x32_bf16(areg[kk], bb, acc[nt], 0, 0, 0);
            }
        }
        bool isq = (o0 < 128);
        #pragma unroll
        for (int nt = 0; nt < 4; nt++) {
            int o = o0 + nt * 16 + m;
            float bs = bias[o];
            int sec = o >> 7;
            int oc = o & 127;
            unsigned short* dst = qkv + (size_t)sec * ((size_t)N_VOX * 128);
            #pragma unroll
            for (int r = 0; r < 4; r++) {
                int vg = v0 + wvi * 16 + quad * 4 + r;
                float val = acc[nt][r] + bs;
                if (isq) val *= 0.17677669529663687f;
                dst[(size_t)vg * 128 + oc] = f2bf(val);
            }
        }
        __syncthreads();
    }
}

// -------- Kernel 2: neighborhood attention via MFMA (XCD-swizzled) --------
// Verified round-5 kernel, unchanged.
#define VT_STRIDE 188
__global__ __launch_bounds__(256) void attn_kernel(const unsigned short* __restrict__ qb,
                                                   const unsigned short* __restrict__ kb,
                                                   const unsigned short* __restrict__ vb,
                                                   unsigned short* __restrict__ ob) {
    __shared__ unsigned int vjtab[176];                      // region idx -> voxel idx
    __shared__ __align__(16) unsigned short vt[4][32 * VT_STRIDE];  // per-head V^T slice

    int t = threadIdx.x;
    // XCD-aware swizzle (bijective: 2048 = 8 XCDs x 256 blocks)
    int hw = blockIdx.x;
    int bidx = (hw & 7) * 256 + (hw >> 3);
    int zh = bidx & 1, yy = (bidx >> 1) & 31, xx = bidx >> 6;
    int z0 = zh << 4;
    int sx = min(max(xx - 1, 0), 29);
    int sy = min(max(yy - 1, 0), 29);
    int zr0 = min(max(z0 - 1, 0), 14);
    int vox0 = (xx << 10) + (yy << 5) + z0;

    if (t < 176) {
        int r = t < 162 ? t : 161;
        int rxy = r / 18;
        int rzv = r - rxy * 18;
        int ax = rxy / 3;
        int by = rxy - ax * 3;
        vjtab[t] = (unsigned)(((sx + ax) << 10) + ((sy + by) << 5) + (zr0 + rzv));
    }
    __syncthreads();

    int wave = t >> 6, lane = t & 63;
    int hq = lane >> 4;        // quad (k-chunk / row-chunk index)
    int m = lane & 15;
    int ch0 = wave * 32;

    // ---- stage V^T slice for this head: vt[wave][ch_local][region] ----
    unsigned short* vts = &vt[wave][0];
    {
        const int cp = m;      // ch-pair index 0..15
        #pragma unroll
        for (int u = 0; u < 11; u++) {
            int rb = u * 16 + hq * 4;
            unsigned int j0 = vjtab[rb + 0];
            unsigned int j1 = vjtab[rb + 1];
            unsigned int j2 = vjtab[rb + 2];
            unsigned int j3 = vjtab[rb + 3];
            unsigned int d0 = *(const unsigned int*)&vb[(size_t)j0 * 128 + ch0 + cp * 2];
            unsigned int d1 = *(const unsigned int*)&vb[(size_t)j1 * 128 + ch0 + cp * 2];
            unsigned int d2 = *(const unsigned int*)&vb[(size_t)j2 * 128 + ch0 + cp * 2];
            unsigned int d3 = *(const unsigned int*)&vb[(size_t)j3 * 128 + ch0 + cp * 2];
            if (u == 10) {     // zero pad rows [162,176) (NaN-safety for P*V)
                if (rb + 0 >= 162) d0 = 0u;
                if (rb + 1 >= 162) d1 = 0u;
                if (rb + 2 >= 162) d2 = 0u;
                if (rb + 3 >= 162) d3 = 0u;
            }
            unsigned int lo01 = __builtin_amdgcn_perm(d1, d0, 0x05040100u);
            unsigned int lo23 = __builtin_amdgcn_perm(d3, d2, 0x05040100u);
            unsigned int hi01 = __builtin_amdgcn_perm(d1, d0, 0x07060302u);
            unsigned int hi23 = __builtin_amdgcn_perm(d3, d2, 0x07060302u);
            u32x2 wlo; wlo.x = lo01; wlo.y = lo23;
            u32x2 whi; whi.x = hi01; whi.y = hi23;
            *(u32x2*)&vts[(2 * cp) * VT_STRIDE + rb] = wlo;
            *(u32x2*)&vts[(2 * cp + 1) * VT_STRIDE + rb] = whi;
        }
    }

    // ---- QK^T: S^T[r][v] = sum_ch K[vj(r)][ch] * Q[v][ch]  (Q pre-scaled) ----
    bfrag qf = *(const bfrag*)&qb[(size_t)(vox0 + m) * 128 + ch0 + hq * 8];
    ffrag s[11];
    #pragma unroll
    for (int f = 0; f < 11; f++) {
        unsigned int vj = vjtab[f * 16 + m];
        bfrag kf = *(const bfrag*)&kb[(size_t)vj * 128 + ch0 + hq * 8];
        s[f] = __builtin_amdgcn_mfma_f32_16x16x32_bf16(kf, qf, ffrag{0,0,0,0}, 0, 0, 0);
    }

    // ---- mask (z-window + r<162) + softmax over region, per voxel v = lane&15 ----
    int zv = z0 + m;
    int szv = min(max(zv - 1, 0), 29);
    unsigned int wz = (unsigned int)(szv - zr0);
    unsigned int rz = 4u * (unsigned int)hq;   // rz(r) for r = 16f + 4*hq, f=0
    float mx = -1e30f;
    #pragma unroll
    for (int f = 0; f < 11; f++) {
        #pragma unroll
        for (int i = 0; i < 4; i++) {
            unsigned int ri = rz + (unsigned int)i;
            ri = min(ri, ri - 18u);            // mod-18 wrap (single-wrap trick)
            bool valid = (ri - wz) <= 2u;      // unsigned window test
            if (f == 10) valid = valid && ((4 * hq + i) < 2);  // r < 162
            float sv = valid ? s[f][i] : -1e30f;
            s[f][i] = sv;
            mx = fmaxf(mx, sv);
        }
        rz = min(rz + 16u, rz - 2u);           // (rz+16) mod 18
    }
    mx = fmaxf(mx, __shfl_xor(mx, 16));
    mx = fmaxf(mx, __shfl_xor(mx, 32));
    float sum = 0.f;
    #pragma unroll
    for (int f = 0; f < 11; f++) {
        #pragma unroll
        for (int i = 0; i < 4; i++) {
            float p = __expf(s[f][i] - mx);
            s[f][i] = p;
            sum += p;
        }
    }
    sum += __shfl_xor(sum, 16);
    sum += __shfl_xor(sum, 32);
    float inv = 1.0f / sum;

    // ---- PV: O^T[ch][v] = sum_r V^T[ch][r] * P^T[r][v], P from regs ----
    ffrag acc0 = ffrag{0,0,0,0};
    ffrag acc1 = ffrag{0,0,0,0};
    const unsigned short* ab = &vt[wave][m * VT_STRIDE + hq * 4];
    #pragma unroll
    for (int f = 0; f < 11; f++) {
        u32x2 pb; pb.x = cvtpk(s[f][0], s[f][1]); pb.y = cvtpk(s[f][2], s[f][3]);
        u32x2 av0 = *(const u32x2*)&ab[f * 16];
        u32x2 av1 = *(const u32x2*)&ab[16 * VT_STRIDE + f * 16];
        asm("v_mfma_f32_16x16x16_bf16 %0, %1, %2, %0" : "+v"(acc0) : "v"(av0), "v"(pb));
        asm("v_mfma_f32_16x16x16_bf16 %0, %1, %2, %0" : "+v"(acc1) : "v"(av1), "v"(pb));
    }

    // ---- epilogue: scale by 1/sum, pack bf16, store O[vox][ch] ----
    size_t obase = (size_t)(vox0 + m) * 128 + ch0 + hq * 4;
    {
        u32x2 ov;
        ov.x = cvtpk(acc0[0] * inv, acc0[1] * inv);
        ov.y = cvtpk(acc0[2] * inv, acc0[3] * inv);
        *(u32x2*)&ob[obase] = ov;
    }
    {
        u32x2 ov;
        ov.x = cvtpk(acc1[0] * inv, acc1[1] * inv);
        ov.y = cvtpk(acc1[2] * inv, acc1[3] * inv);
        *(u32x2*)&ob[obase + 16] = ov;
    }
}

// -------- Kernel 3: proj GEMM + bias + residual + transpose to (C, N) --------
__global__ __launch_bounds__(256) void proj_gemm(const unsigned short* __restrict__ a,
                                                 const float* __restrict__ w,
                                                 const float* __restrict__ bias,
                                                 const float* __restrict__ xres,
                                                 float* __restrict__ out) {
    __shared__ __align__(16) unsigned short a_s[64 * 136];
    __shared__ __align__(16) unsigned short b_s[64 * 136];
    int t = threadIdx.x;
    int m0 = blockIdx.x * 64, o0 = blockIdx.y * 64;
    {
        int r4 = t >> 4, c8 = t & 15;
        #pragma unroll
        for (int pass = 0; pass < 4; pass++) {
            int r = pass * 16 + r4;
            *(uint4*)&a_s[r * 136 + c8 * 8] =
                *(const uint4*)&a[(size_t)(m0 + r) * 128 + c8 * 8];
            float4 w0 = *(const float4*)&w[(size_t)(o0 + r) * 128 + c8 * 8];
            float4 w1 = *(const float4*)&w[(size_t)(o0 + r) * 128 + c8 * 8 + 4];
            uint4 q;
            q.x = cvtpk(w0.x, w0.y);
            q.y = cvtpk(w0.z, w0.w);
            q.z = cvtpk(w1.x, w1.y);
            q.w = cvtpk(w1.z, w1.w);
            *(uint4*)&b_s[r * 136 + c8 * 8] = q;
        }
    }
    __syncthreads();
    int wvi = t >> 6, lane = t & 63, m = lane & 15, quad = lane >> 4;
    ffrag acc[4] = {ffrag{0,0,0,0}, ffrag{0,0,0,0}, ffrag{0,0,0,0}, ffrag{0,0,0,0}};
    #pragma unroll
    for (int kk = 0; kk < 4; kk++) {
        bfrag av = *(bfrag*)&a_s[(wvi * 16 + m) * 136 + kk * 32 + quad * 8];
        #pragma unroll
        for (int nt = 0; nt < 4; nt++) {
            bfrag bb = *(bfrag*)&b_s[(nt * 16 + m) * 136 + kk * 32 + quad * 8];
            acc[nt] = __builtin_amdgcn_mfma_f32_16x16x32_bf16(av, bb, acc[nt], 0, 0, 0);
        }
    }
    #pragma unroll
    for (int nt = 0; nt < 4; nt++) {
        int o = o0 + nt * 16 + m;
        float bs = bias[o];
        int vg = m0 + wvi * 16 + quad * 4;
        float4 r = *(const float4*)&xres[(size_t)o * N_VOX + vg];
        float4 ov;
        ov.x = acc[nt][0] + bs + r.x;
        ov.y = acc[nt][1] + bs + r.y;
        ov.z = acc[nt][2] + bs + r.z;
        ov.w = acc[nt][3] + bs + r.w;
        *(float4*)&out[(size_t)o * N_VOX + vg] = ov;
    }
}

extern "C" void kernel_launch(void* const* d_in, const int* in_sizes, int n_in,
                              void* d_out, int out_size, void* d_ws, size_t ws_size,
                              hipStream_t stream) {
    const float* x      = (const float*)d_in[0];
    const float* gamma  = (const float*)d_in[1];
    const float* beta   = (const float*)d_in[2];
    const float* qkv_w  = (const float*)d_in[3];
    const float* qkv_b  = (const float*)d_in[4];
    const float* proj_w = (const float*)d_in[5];
    const float* proj_b = (const float*)d_in[6];
    float* out = (float*)d_out;

    unsigned short* qkv  = (unsigned short*)d_ws;                            // 24 MB
    unsigned short* attn = (unsigned short*)((char*)d_ws + (24u << 20));     // 8 MB

    hipLaunchKernelGGL(ln_qkv, dim3(2, 512), dim3(256), 0, stream,
                       x, gamma, beta, qkv_w, qkv_b, qkv);
    const unsigned short* qb = qkv;
    const unsigned short* kb = qkv + (size_t)N_VOX * 128;
    const unsigned short* vb = qkv + (size_t)2 * N_VOX * 128;
    hipLaunchKernelGGL(attn_kernel, dim3(2048), dim3(256), 0, stream, qb, kb, vb, attn);
    hipLaunchKernelGGL(proj_gemm, dim3(512, 2), dim3(256), 0, stream, attn, proj_w, proj_b, x, out);
}

// Round 7
// 112.565 us; speedup vs baseline: 1.1505x; 1.0502x over previous
//
#include <hip/hip_runtime.h>

#define N_VOX 32768
#define CCH 128
#define EPSV 1e-5f

typedef __attribute__((ext_vector_type(8))) short bfrag;
typedef __attribute__((ext_vector_type(4))) float ffrag;
typedef __attribute__((ext_vector_type(2))) unsigned int u32x2;

__device__ __forceinline__ float bf2f(unsigned short u) {
    union { unsigned int i; float f; } c; c.i = ((unsigned int)u) << 16; return c.f;
}
__device__ __forceinline__ unsigned short f2bf(float f) {
    union { float f; unsigned int i; } c; c.f = f;
    unsigned int i = c.i;
    return (unsigned short)((i + 0x7FFFu + ((i >> 16) & 1u)) >> 16);
}
__device__ __forceinline__ unsigned int cvtpk(float lo, float hi) {
    unsigned int r;
    asm("v_cvt_pk_bf16_f32 %0, %1, %2" : "=v"(r) : "v"(lo), "v"(hi));
    return r;
}

// -------- Kernel 1: fused LayerNorm + QKV GEMM (verified round-6) --------
__global__ __launch_bounds__(256) void ln_qkv(const float* __restrict__ x,
                                              const float* __restrict__ gamma,
                                              const float* __restrict__ beta,
                                              const float* __restrict__ w,
                                              const float* __restrict__ bias,
                                              unsigned short* __restrict__ qkv) {
    __shared__ __align__(16) unsigned short a_s[64 * 136];
    __shared__ __align__(16) unsigned short b_s[64 * 136];
    __shared__ float ps[256], pq[256];
    __shared__ float muS[64], rsS[64];
    __shared__ float g[128], bta[128];
    int t = threadIdx.x;
    int og = blockIdx.x;            // o-group: tiles og*192 .. og*192+191
    int v0 = blockIdx.y * 64;
    if (t < 128) { g[t] = gamma[t]; bta[t] = beta[t]; }
    int cq = t >> 6, v = t & 63;
    // ---- LN phase: each wave owns 32 channels, all 64 voxels ----
    float xr[32];
    float s = 0.f, sq = 0.f;
    #pragma unroll
    for (int i = 0; i < 32; i++) {
        float val = x[(size_t)(cq * 32 + i) * N_VOX + v0 + v];
        xr[i] = val; s += val; sq += val * val;
    }
    ps[t] = s; pq[t] = sq;
    __syncthreads();
    if (t < 64) {
        float S = ps[t] + ps[t + 64] + ps[t + 128] + ps[t + 192];
        float Q = pq[t] + pq[t + 64] + pq[t + 128] + pq[t + 192];
        float mu = S * (1.0f / 128.0f);
        float var = Q * (1.0f / 128.0f) - mu * mu;
        muS[t] = mu; rsS[t] = rsqrtf(var + EPSV);
    }
    __syncthreads();
    {
        float mu = muS[v], rs = rsS[v];
        #pragma unroll
        for (int i8 = 0; i8 < 4; i8++) {
            float val[8];
            #pragma unroll
            for (int k = 0; k < 8; k++) {
                int c = cq * 32 + i8 * 8 + k;
                val[k] = (xr[i8 * 8 + k] - mu) * rs * g[c] + bta[c];
            }
            uint4 q;
            q.x = cvtpk(val[0], val[1]);
            q.y = cvtpk(val[2], val[3]);
            q.z = cvtpk(val[4], val[5]);
            q.w = cvtpk(val[6], val[7]);
            *(uint4*)&a_s[v * 136 + cq * 32 + i8 * 8] = q;
        }
    }
    __syncthreads();
    // ---- GEMM phase: 3 o-tiles of 64 ----
    int lane = t & 63, wvi = t >> 6, m = lane & 15, quad = lane >> 4;
    bfrag areg[4];
    #pragma unroll
    for (int kk = 0; kk < 4; kk++)
        areg[kk] = *(bfrag*)&a_s[(wvi * 16 + m) * 136 + kk * 32 + quad * 8];
    for (int t0 = 0; t0 < 3; t0++) {
        int o0 = og * 192 + t0 * 64;
        {
            int r4 = t >> 4, c8 = t & 15;
            #pragma unroll
            for (int pass = 0; pass < 4; pass++) {
                int r = pass * 16 + r4;
                float4 w0 = *(const float4*)&w[(size_t)(o0 + r) * 128 + c8 * 8];
                float4 w1 = *(const float4*)&w[(size_t)(o0 + r) * 128 + c8 * 8 + 4];
                uint4 q;
                q.x = cvtpk(w0.x, w0.y);
                q.y = cvtpk(w0.z, w0.w);
                q.z = cvtpk(w1.x, w1.y);
                q.w = cvtpk(w1.z, w1.w);
                *(uint4*)&b_s[r * 136 + c8 * 8] = q;
            }
        }
        __syncthreads();
        ffrag acc[4] = {ffrag{0,0,0,0}, ffrag{0,0,0,0}, ffrag{0,0,0,0}, ffrag{0,0,0,0}};
        #pragma unroll
        for (int kk = 0; kk < 4; kk++) {
            #pragma unroll
            for (int nt = 0; nt < 4; nt++) {
                bfrag bb = *(bfrag*)&b_s[(nt * 16 + m) * 136 + kk * 32 + quad * 8];
                acc[nt] = __builtin_amdgcn_mfma_f32_16x16x32_bf16(areg[kk], bb, acc[nt], 0, 0, 0);
            }
        }
        bool isq = (o0 < 128);
        #pragma unroll
        for (int nt = 0; nt < 4; nt++) {
            int o = o0 + nt * 16 + m;
            float bs = bias[o];
            int sec = o >> 7;
            int oc = o & 127;
            unsigned short* dst = qkv + (size_t)sec * ((size_t)N_VOX * 128);
            #pragma unroll
            for (int r = 0; r < 4; r++) {
                int vg = v0 + wvi * 16 + quad * 4 + r;
                float val = acc[nt][r] + bs;
                if (isq) val *= 0.17677669529663687f;
                dst[(size_t)vg * 128 + oc] = f2bf(val);
            }
        }
        __syncthreads();
    }
}

// -------- Kernel 2: neighborhood attention via MFMA, 2x2x4-cube tiling --------
// Block = one 2x2x4 voxel cube (16 voxels), 4 waves = 4 heads. Region =
// 4x4x6 = 96 K/V rows = EXACTLY 6 MFMA fragments (no padding tail).
// Density 27/96 = 28% (vs 27/162 for the old z-column), so staging loads
// 44->24, QK MFMAs 11->6, PV MFMAs 22->12, softmax s-values 44->24, and
// LDS 48.8KB -> 25.7KB (3 -> 4+ blocks/CU). Masking is 3-axis, done via a
// per-region 16-bit voxel-validity table (vmsk) built once per block by
// 96 threads — per s-value cost is one broadcast LDS read + bit test.
// Invalid entries get -1e30 -> exp()=0, so no V zero-padding is needed
// (all 96 region rows are real in-grid voxels). XCD swizzle kept.
#define VT2 100
__global__ __launch_bounds__(256) void attn_kernel(const unsigned short* __restrict__ qb,
                                                   const unsigned short* __restrict__ kb,
                                                   const unsigned short* __restrict__ vb,
                                                   unsigned short* __restrict__ ob) {
    __shared__ unsigned int vjtab[96];                    // region idx -> voxel idx
    __shared__ __align__(16) unsigned int vmsk[96];       // region idx -> 16-bit voxel validity
    __shared__ __align__(16) unsigned short vt[4][32 * VT2];  // per-head V^T slice

    int t = threadIdx.x;
    // XCD-aware swizzle (bijective: 2048 = 8 XCDs x 256 blocks)
    int hw = blockIdx.x;
    int bidx = (hw & 7) * 256 + (hw >> 3);
    // cube coords: 16 x 16 x 8 cubes of 2x2x4 voxels
    int czi = bidx & 7, cyi = (bidx >> 3) & 15, cxi = bidx >> 7;
    int cx0 = cxi << 1, cy0 = cyi << 1, cz0 = czi << 2;
    int rx0 = min(max(cx0 - 1, 0), 28);   // region origin (4 wide in x,y)
    int ry0 = min(max(cy0 - 1, 0), 28);
    int rz0 = min(max(cz0 - 1, 0), 26);   // 6 wide in z

    if (t < 96) {
        int r = t;
        int ax = r / 24;
        int rem = r - ax * 24;
        int by = rem / 6;
        int cz = rem - by * 6;
        vjtab[t] = (unsigned)(((rx0 + ax) << 10) + ((ry0 + by) << 5) + (rz0 + cz));
        // validity of region (ax,by,cz) for each of the 16 voxels
        int wx0 = min(max(cx0 - 1, 0), 29) - rx0;   // vx=0 window start (rel)
        int wx1 = min(cx0, 29) - rx0;               // vx=1
        int wy0 = min(max(cy0 - 1, 0), 29) - ry0;
        int wy1 = min(cy0, 29) - ry0;
        unsigned zn = 0;
        #pragma unroll
        for (int vz = 0; vz < 4; vz++) {
            int wz = min(max(cz0 + vz - 1, 0), 29) - rz0;
            if ((unsigned)(cz - wz) <= 2u) zn |= 1u << vz;
        }
        bool x0 = (unsigned)(ax - wx0) <= 2u;
        bool x1 = (unsigned)(ax - wx1) <= 2u;
        bool y0 = (unsigned)(by - wy0) <= 2u;
        bool y1 = (unsigned)(by - wy1) <= 2u;
        unsigned msk = 0;
        if (x0 && y0) msk |= zn;            // voxel bit m = vx*8 + vy*4 + vz
        if (x0 && y1) msk |= zn << 4;
        if (x1 && y0) msk |= zn << 8;
        if (x1 && y1) msk |= zn << 12;
        vmsk[t] = msk;
    }
    __syncthreads();

    int wave = t >> 6, lane = t & 63;
    int hq = lane >> 4;        // quad (k-chunk / row-chunk index)
    int m = lane & 15;
    int ch0 = wave * 32;

    // ---- stage V^T slice for this head: vt[wave][ch_local][region] ----
    unsigned short* vts = &vt[wave][0];
    {
        const int cp = m;      // ch-pair index 0..15
        #pragma unroll
        for (int u = 0; u < 6; u++) {
            int rb = u * 16 + hq * 4;
            unsigned int j0 = vjtab[rb + 0];
            unsigned int j1 = vjtab[rb + 1];
            unsigned int j2 = vjtab[rb + 2];
            unsigned int j3 = vjtab[rb + 3];
            unsigned int d0 = *(const unsigned int*)&vb[(size_t)j0 * 128 + ch0 + cp * 2];
            unsigned int d1 = *(const unsigned int*)&vb[(size_t)j1 * 128 + ch0 + cp * 2];
            unsigned int d2 = *(const unsigned int*)&vb[(size_t)j2 * 128 + ch0 + cp * 2];
            unsigned int d3 = *(const unsigned int*)&vb[(size_t)j3 * 128 + ch0 + cp * 2];
            unsigned int lo01 = __builtin_amdgcn_perm(d1, d0, 0x05040100u);
            unsigned int lo23 = __builtin_amdgcn_perm(d3, d2, 0x05040100u);
            unsigned int hi01 = __builtin_amdgcn_perm(d1, d0, 0x07060302u);
            unsigned int hi23 = __builtin_amdgcn_perm(d3, d2, 0x07060302u);
            u32x2 wlo; wlo.x = lo01; wlo.y = lo23;
            u32x2 whi; whi.x = hi01; whi.y = hi23;
            *(u32x2*)&vts[(2 * cp) * VT2 + rb] = wlo;
            *(u32x2*)&vts[(2 * cp + 1) * VT2 + rb] = whi;
        }
    }

    // ---- this lane's voxel: m = vx*8 + vy*4 + vz ----
    int gx = cx0 + (m >> 3), gy = cy0 + ((m >> 2) & 1), gz = cz0 + (m & 3);
    int vox = (gx << 10) + (gy << 5) + gz;

    // ---- QK^T: S^T[r][v] = sum_ch K[vj(r)][ch] * Q[v][ch]  (Q pre-scaled) ----
    bfrag qf = *(const bfrag*)&qb[(size_t)vox * 128 + ch0 + hq * 8];
    ffrag s[6];
    #pragma unroll
    for (int f = 0; f < 6; f++) {
        unsigned int vj = vjtab[f * 16 + m];
        bfrag kf = *(const bfrag*)&kb[(size_t)vj * 128 + ch0 + hq * 8];
        s[f] = __builtin_amdgcn_mfma_f32_16x16x32_bf16(kf, qf, ffrag{0,0,0,0}, 0, 0, 0);
    }

    // ---- mask via table + softmax, per voxel v = lane&15 ----
    // s[f][i] corresponds to region r = f*16 + 4*hq + i
    float mx = -1e30f;
    #pragma unroll
    for (int f = 0; f < 6; f++) {
        uint4 mk = *(const uint4*)&vmsk[f * 16 + hq * 4];
        unsigned mm[4] = {mk.x, mk.y, mk.z, mk.w};
        #pragma unroll
        for (int i = 0; i < 4; i++) {
            bool valid = (mm[i] >> m) & 1u;
            float sv = valid ? s[f][i] : -1e30f;
            s[f][i] = sv;
            mx = fmaxf(mx, sv);
        }
    }
    mx = fmaxf(mx, __shfl_xor(mx, 16));
    mx = fmaxf(mx, __shfl_xor(mx, 32));
    float sum = 0.f;
    #pragma unroll
    for (int f = 0; f < 6; f++) {
        #pragma unroll
        for (int i = 0; i < 4; i++) {
            float p = __expf(s[f][i] - mx);
            s[f][i] = p;
            sum += p;
        }
    }
    sum += __shfl_xor(sum, 16);
    sum += __shfl_xor(sum, 32);
    float inv = 1.0f / sum;

    // ---- PV: O^T[ch][v] = sum_r V^T[ch][r] * P^T[r][v], P from regs ----
    ffrag acc0 = ffrag{0,0,0,0};
    ffrag acc1 = ffrag{0,0,0,0};
    const unsigned short* ab = &vt[wave][m * VT2 + hq * 4];
    #pragma unroll
    for (int f = 0; f < 6; f++) {
        u32x2 pb; pb.x = cvtpk(s[f][0], s[f][1]); pb.y = cvtpk(s[f][2], s[f][3]);
        u32x2 av0 = *(const u32x2*)&ab[f * 16];
        u32x2 av1 = *(const u32x2*)&ab[16 * VT2 + f * 16];
        asm("v_mfma_f32_16x16x16_bf16 %0, %1, %2, %0" : "+v"(acc0) : "v"(av0), "v"(pb));
        asm("v_mfma_f32_16x16x16_bf16 %0, %1, %2, %0" : "+v"(acc1) : "v"(av1), "v"(pb));
    }

    // ---- epilogue: scale by 1/sum, pack bf16, store O[vox][ch] ----
    size_t obase = (size_t)vox * 128 + ch0 + hq * 4;
    {
        u32x2 ov;
        ov.x = cvtpk(acc0[0] * inv, acc0[1] * inv);
        ov.y = cvtpk(acc0[2] * inv, acc0[3] * inv);
        *(u32x2*)&ob[obase] = ov;
    }
    {
        u32x2 ov;
        ov.x = cvtpk(acc1[0] * inv, acc1[1] * inv);
        ov.y = cvtpk(acc1[2] * inv, acc1[3] * inv);
        *(u32x2*)&ob[obase + 16] = ov;
    }
}

// -------- Kernel 3: proj GEMM + bias + residual + transpose to (C, N) --------
__global__ __launch_bounds__(256) void proj_gemm(const unsigned short* __restrict__ a,
                                                 const float* __restrict__ w,
                                                 const float* __restrict__ bias,
                                                 const float* __restrict__ xres,
                                                 float* __restrict__ out) {
    __shared__ __align__(16) unsigned short a_s[64 * 136];
    __shared__ __align__(16) unsigned short b_s[64 * 136];
    int t = threadIdx.x;
    int m0 = blockIdx.x * 64, o0 = blockIdx.y * 64;
    {
        int r4 = t >> 4, c8 = t & 15;
        #pragma unroll
        for (int pass = 0; pass < 4; pass++) {
            int r = pass * 16 + r4;
            *(uint4*)&a_s[r * 136 + c8 * 8] =
                *(const uint4*)&a[(size_t)(m0 + r) * 128 + c8 * 8];
            float4 w0 = *(const float4*)&w[(size_t)(o0 + r) * 128 + c8 * 8];
            float4 w1 = *(const float4*)&w[(size_t)(o0 + r) * 128 + c8 * 8 + 4];
            uint4 q;
            q.x = cvtpk(w0.x, w0.y);
            q.y = cvtpk(w0.z, w0.w);
            q.z = cvtpk(w1.x, w1.y);
            q.w = cvtpk(w1.z, w1.w);
            *(uint4*)&b_s[r * 136 + c8 * 8] = q;
        }
    }
    __syncthreads();
    int wvi = t >> 6, lane = t & 63, m = lane & 15, quad = lane >> 4;
    ffrag acc[4] = {ffrag{0,0,0,0}, ffrag{0,0,0,0}, ffrag{0,0,0,0}, ffrag{0,0,0,0}};
    #pragma unroll
    for (int kk = 0; kk < 4; kk++) {
        bfrag av = *(bfrag*)&a_s[(wvi * 16 + m) * 136 + kk * 32 + quad * 8];
        #pragma unroll
        for (int nt = 0; nt < 4; nt++) {
            bfrag bb = *(bfrag*)&b_s[(nt * 16 + m) * 136 + kk * 32 + quad * 8];
            acc[nt] = __builtin_amdgcn_mfma_f32_16x16x32_bf16(av, bb, acc[nt], 0, 0, 0);
        }
    }
    #pragma unroll
    for (int nt = 0; nt < 4; nt++) {
        int o = o0 + nt * 16 + m;
        float bs = bias[o];
        int vg = m0 + wvi * 16 + quad * 4;
        float4 r = *(const float4*)&xres[(size_t)o * N_VOX + vg];
        float4 ov;
        ov.x = acc[nt][0] + bs + r.x;
        ov.y = acc[nt][1] + bs + r.y;
        ov.z = acc[nt][2] + bs + r.z;
        ov.w = acc[nt][3] + bs + r.w;
        *(float4*)&out[(size_t)o * N_VOX + vg] = ov;
    }
}

extern "C" void kernel_launch(void* const* d_in, const int* in_sizes, int n_in,
                              void* d_out, int out_size, void* d_ws, size_t ws_size,
                              hipStream_t stream) {
    const float* x      = (const float*)d_in[0];
    const float* gamma  = (const float*)d_in[1];
    const float* beta   = (const float*)d_in[2];
    const float* qkv_w  = (const float*)d_in[3];
    const float* qkv_b  = (const float*)d_in[4];
    const float* proj_w = (const float*)d_in[5];
    const float* proj_b = (const float*)d_in[6];
    float* out = (float*)d_out;

    unsigned short* qkv  = (unsigned short*)d_ws;                            // 24 MB
    unsigned short* attn = (unsigned short*)((char*)d_ws + (24u << 20));     // 8 MB

    hipLaunchKernelGGL(ln_qkv, dim3(2, 512), dim3(256), 0, stream,
                       x, gamma, beta, qkv_w, qkv_b, qkv);
    const unsigned short* qb = qkv;
    const unsigned short* kb = qkv + (size_t)N_VOX * 128;
    const unsigned short* vb = qkv + (size_t)2 * N_VOX * 128;
    hipLaunchKernelGGL(attn_kernel, dim3(2048), dim3(256), 0, stream, qb, kb, vb, attn);
    hipLaunchKernelGGL(proj_gemm, dim3(512, 2), dim3(256), 0, stream, attn, proj_w, proj_b, x, out);
}